// Round 18
// baseline (184.559 us; speedup 1.0000x reference)
//
#include <hip/hip_runtime.h>
#include <hip/hip_bf16.h>

#define BB 16
#define NI 2048
#define NA 2048
#define DD 256
#define KVB 32
#define NT (NA / KVB)    // 64

typedef _Float16 half8 __attribute__((ext_vector_type(8)));
typedef __attribute__((ext_vector_type(16))) float f32x16;
typedef __attribute__((ext_vector_type(4))) unsigned int uint4v;

typedef const unsigned int CGU __attribute__((address_space(1)));
typedef unsigned int LU __attribute__((address_space(3)));

static __device__ __forceinline__ unsigned short f2h(float f) {
  union { _Float16 h; unsigned short u; } x; x.h = (_Float16)f; return x.u;
}
static __device__ __forceinline__ float h2f(unsigned short u) {
  union { _Float16 h; unsigned short u; } x; x.u = u; return (float)x.h;
}
static __device__ __forceinline__ unsigned int pk2(float a, float b) {
  return __builtin_bit_cast(unsigned int, __builtin_amdgcn_cvt_pkrtz(a, b));
}
static __device__ __forceinline__ float ex2(float x) {
  return __builtin_amdgcn_exp2f(x);
}
static __device__ __forceinline__ void gload16(const unsigned short* g, unsigned short* l) {
  __builtin_amdgcn_global_load_lds((CGU*)g, (LU*)l, 16, 0, 0);
}

// ---------------- prep (+fused tw) ----------------
// kfrag[b][kt][ks(16)][lane(64)][e(8)]: lane holds K[jb + (l&31)][ks*16 + (l>>5)*8 + e]
// vfrag[b][kt][h(2)][dt(4)][m(2)][lane(64)][e(8)]: lane holds
//   V^T[h*128 + dt*32 + (l&31)][jb + (e&3) + 8*(e>>2) + 4*(l>>5) + 16*m]
__global__ void prep_kernel(const float* __restrict__ a,
                            unsigned short* __restrict__ kfrag,
                            unsigned short* __restrict__ vfrag,
                            const float* __restrict__ w,
                            unsigned short* __restrict__ wth,
                            unsigned short* __restrict__ wtl) {
  __shared__ float t[64][65];
  int bx = blockIdx.x;
  int tid = threadIdx.x;
  int rr = tid >> 4, c4 = tid & 15;

  if (bx >= 2048) {
    int r = bx - 2048;
    int dt = r >> 2, et = r & 3;
    int d0 = dt * 64, e0 = et * 64;
    int cc = c4 * 4;
#pragma unroll
    for (int k = 0; k < 4; ++k) {
      int row = rr + k * 16;
      float4 v = *(const float4*)(w + (size_t)(d0 + row) * DD + e0 + cc);
      t[row][cc + 0] = v.x; t[row][cc + 1] = v.y; t[row][cc + 2] = v.z; t[row][cc + 3] = v.w;
    }
    __syncthreads();
#pragma unroll
    for (int k = 0; k < 4; ++k) {
      int e = rr + k * 16;
      int eg = e0 + e;
      ushort4 h, l;
      float v0 = t[cc + 0][e]; h.x = f2h(v0); l.x = f2h(v0 - h2f(h.x));
      float v1 = t[cc + 1][e]; h.y = f2h(v1); l.y = f2h(v1 - h2f(h.y));
      float v2 = t[cc + 2][e]; h.z = f2h(v2); l.z = f2h(v2 - h2f(h.z));
      float v3 = t[cc + 3][e]; h.w = f2h(v3); l.w = f2h(v3 - h2f(h.w));
      int dd = d0 + cc;
      int u = dd >> 3, sub = dd & 7;
      size_t off = (size_t)eg * DD + ((u ^ (eg & 7)) * 8) + sub;
      *(ushort4*)(wth + off) = h;
      *(ushort4*)(wtl + off) = l;
    }
    return;
  }

  int b = bx >> 7;
  int r = bx & 127;
  int jt_t = r >> 2, dt_t = r & 3;
  int j0 = jt_t * 64, d0 = dt_t * 64;
#pragma unroll
  for (int k = 0; k < 4; ++k) {
    int row = rr + k * 16;
    int j = j0 + row;
    int d = d0 + c4 * 4;
    float4 v = *(const float4*)(a + ((size_t)b * NA + j) * DD + d);
    ushort4 hh;
    hh.x = f2h(v.x); hh.y = f2h(v.y); hh.z = f2h(v.z); hh.w = f2h(v.w);
    int kt = j >> 5;
    int ks = d >> 4;
    int lk = (j & 31) + 32 * ((d >> 3) & 1);
    *(ushort4*)(kfrag + (((size_t)b * NT + kt) * 16 + ks) * 512 + lk * 8 + (c4 & 1) * 4) = hh;
    t[row][c4 * 4 + 0] = v.x; t[row][c4 * 4 + 1] = v.y;
    t[row][c4 * 4 + 2] = v.z; t[row][c4 * 4 + 3] = v.w;
  }
  __syncthreads();
#pragma unroll
  for (int k = 0; k < 4; ++k) {
    int dl = rr + k * 16;
    int d = d0 + dl;
    int j = j0 + c4 * 4;
    ushort4 o;
    o.x = f2h(t[c4 * 4 + 0][dl]); o.y = f2h(t[c4 * 4 + 1][dl]);
    o.z = f2h(t[c4 * 4 + 2][dl]); o.w = f2h(t[c4 * 4 + 3][dl]);
    int kt = j >> 5;
    int hi = c4 & 1;
    int m = (c4 >> 2) & 1;
    int ebase = ((c4 >> 1) & 1) * 4;
    int hh_ = d >> 7, dtl = (d >> 5) & 3;
    int lv = (d & 31) + 32 * hi;
    *(ushort4*)(vfrag + ((((((size_t)b * NT + kt) * 2 + hh_) * 4 + dtl) * 2 + m) * 512) + lv * 8 + ebase) = o;
  }
}

// ---------------- Q = (x @ W) * log2(e) (2-term fp16 MFMA), qf row-major ----------------
__global__ __launch_bounds__(256, 2) void qgemm_kernel(
    const float* __restrict__ x, const unsigned short* __restrict__ wth,
    const unsigned short* __restrict__ wtl, unsigned short* __restrict__ qf) {
  __shared__ unsigned short wb[2][64 * 256];
  const int tid = threadIdx.x;
  const int lane = tid & 63;
  const int wv = tid >> 6;
  const int quad = lane >> 4;
  const int l16 = lane & 15;
  const int m0 = blockIdx.x * 64;

  half8 xf[8];
  {
    const float* xr = x + (size_t)(m0 + wv * 16 + l16) * DD;
#pragma unroll
    for (int c = 0; c < 8; ++c) {
      float4 a = *(const float4*)(xr + c * 32 + quad * 8);
      float4 b = *(const float4*)(xr + c * 32 + quad * 8 + 4);
      half8 v;
      v[0] = (_Float16)a.x; v[1] = (_Float16)a.y; v[2] = (_Float16)a.z; v[3] = (_Float16)a.w;
      v[4] = (_Float16)b.x; v[5] = (_Float16)b.y; v[6] = (_Float16)b.z; v[7] = (_Float16)b.w;
      xf[c] = v;
    }
  }

#pragma unroll 1
  for (int eg = 0; eg < 4; ++eg) {
    uint4 t0[8], t1[8];
    {
      const unsigned short* sh = wth + (size_t)(eg * 64) * DD;
      const unsigned short* sl = wtl + (size_t)(eg * 64) * DD;
#pragma unroll
      for (int i = 0; i < 8; ++i) {
        t0[i] = *(const uint4*)(sh + (i * 256 + tid) * 8);
        t1[i] = *(const uint4*)(sl + (i * 256 + tid) * 8);
      }
    }
    __syncthreads();
#pragma unroll
    for (int i = 0; i < 8; ++i) {
      *(uint4*)(wb[0] + (i * 256 + tid) * 8) = t0[i];
      *(uint4*)(wb[1] + (i * 256 + tid) * 8) = t1[i];
    }
    __syncthreads();
#pragma unroll
    for (int etl = 0; etl < 4; ++etl) {
      int rloc = etl * 16 + l16;
      typedef __attribute__((ext_vector_type(4))) float f32x4;
      f32x4 acc; acc[0] = acc[1] = acc[2] = acc[3] = 0.f;
#pragma unroll
      for (int c = 0; c < 8; ++c) {
        int off = rloc * DD + (((4 * c + quad) ^ (rloc & 7)) * 8);
        half8 wh = *(const half8*)(wb[0] + off);
        half8 wl = *(const half8*)(wb[1] + off);
        acc = __builtin_amdgcn_mfma_f32_16x16x32_f16(xf[c], wh, acc, 0, 0, 0);
        acc = __builtin_amdgcn_mfma_f32_16x16x32_f16(xf[c], wl, acc, 0, 0, 0);
      }
      int e = eg * 64 + etl * 16 + l16;
#pragma unroll
      for (int rg = 0; rg < 4; ++rg) {
        qf[(size_t)(m0 + wv * 16 + 4 * quad + rg) * DD + e] = f2h(acc[rg] * 1.44269504f);
      }
    }
  }
}

// ---------------- flash attention v18: v16 + 1-tile score pipeline (T15) ----------------
// Iteration kt: [V(kt) loads] [DMA K(kt+2)] [QK^T(kt+1) MFMA] [softmax(kt) VALU]
// [PV(kt) MFMA]. QK^T(kt+1) has no dependency on softmax(kt) -> MFMA and VALU pipes
// overlap. One barrier/kt, full-body DMA cover. In-lane softmax, zero-shuffle P.
__global__ __launch_bounds__(256, 2) void attn_kernel(
    const unsigned short* __restrict__ kfrag, const unsigned short* __restrict__ vfrag,
    const unsigned short* __restrict__ qf, float* __restrict__ out) {
  __shared__ unsigned short kls[2][KVB * DD];   // 2 x 16 KB

  const int tid = threadIdx.x;
  const int lane = tid & 63;
  const int wv = tid >> 6;       // 0..3
  const int pr = wv >> 1;        // pair -> q-group
  const int h = wv & 1;          // d-half
  const int l31 = lane & 31;
  const int hi = lane >> 5;

  int bx = blockIdx.x;
  int lbx = (bx & 7) * 64 + (bx >> 3);   // XCD-chunked (512 = 8*64)
  const int b = lbx >> 5;
  const int qbase = (lbx & 31) * 64 + pr * 32;

  const unsigned short* kfb = kfrag + (size_t)b * NT * 8192;

  // Q B-fragments (32 q x 256 k)
  half8 qh[16];
  {
    const unsigned short* qr = qf + ((size_t)b * NI + qbase + l31) * DD + hi * 8;
#pragma unroll
    for (int ks = 0; ks < 16; ++ks)
      qh[ks] = *(const half8*)(qr + ks * 16);
  }

  f32x16 acc[4];
#pragma unroll
  for (int dt = 0; dt < 4; ++dt)
#pragma unroll
    for (int i = 0; i < 16; ++i) acc[dt][i] = 0.f;
  float m0r = -INFINITY;
  float l0 = 0.f;

  const unsigned short* vp = vfrag + (((size_t)b * NT * 2 + h) * 4) * 1024 + lane * 8;
  const unsigned short* sp = kfb + 16384 + (wv * 512 + lane * 8);   // DMA src for kt+2

  // prologue: DMA tile 0 -> kls[0]; QK^T(0); DMA tile 1 -> kls[1]
#pragma unroll
  for (int i = 0; i < 4; ++i) {
    int off = (i * 4 + wv) * 512;
    gload16(kfb + off + lane * 8, &kls[0][off]);
  }
  __syncthreads();   // tile 0 ready
#pragma unroll
  for (int i = 0; i < 4; ++i) {
    int off = (i * 4 + wv) * 512;
    gload16(kfb + 8192 + off + lane * 8, &kls[1][off]);
  }
  float p[16];
  {
    f32x16 sA, sB;
#pragma unroll
    for (int i = 0; i < 16; ++i) { sA[i] = 0.f; sB[i] = 0.f; }
#pragma unroll
    for (int ks = 0; ks < 8; ++ks) {
      half8 ka = *(const half8*)(&kls[0][ks * 512] + lane * 8);
      sA = __builtin_amdgcn_mfma_f32_32x32x16_f16(ka, qh[ks], sA, 0, 0, 0);
    }
#pragma unroll
    for (int ks = 8; ks < 16; ++ks) {
      half8 ka = *(const half8*)(&kls[0][ks * 512] + lane * 8);
      sB = __builtin_amdgcn_mfma_f32_32x32x16_f16(ka, qh[ks], sB, 0, 0, 0);
    }
#pragma unroll
    for (int i = 0; i < 16; ++i) p[i] = sA[i] + sB[i];
  }
  __syncthreads();   // tile 1 ready

#pragma unroll 1
  for (int kt = 0; kt < NT; ++kt) {
    // ---- V frags for tile kt (own d-half) ----
    half8 vb[8];
#pragma unroll
    for (int i = 0; i < 8; ++i)
      vb[i] = *(const half8*)(vp + i * 512);

    // ---- DMA K(kt+2) into kls[kt&1] (its tile-kt contents consumed last iter) ----
    if (kt + 2 < NT) {
      unsigned short* d = &kls[kt & 1][wv * 512];
      gload16(sp + 0 * 2048, d + 0 * 2048);
      gload16(sp + 1 * 2048, d + 1 * 2048);
      gload16(sp + 2 * 2048, d + 2 * 2048);
      gload16(sp + 3 * 2048, d + 3 * 2048);
    }

    // ---- QK^T(kt+1): independent of softmax(kt) below -> pipes overlap ----
    f32x16 sA, sB;
    if (kt + 1 < NT) {
      const unsigned short* kb = &kls[(kt + 1) & 1][0];
#pragma unroll
      for (int i = 0; i < 16; ++i) { sA[i] = 0.f; sB[i] = 0.f; }
      __builtin_amdgcn_s_setprio(1);
#pragma unroll
      for (int ks = 0; ks < 8; ++ks) {
        half8 ka = *(const half8*)(kb + ks * 512 + lane * 8);
        sA = __builtin_amdgcn_mfma_f32_32x32x16_f16(ka, qh[ks], sA, 0, 0, 0);
      }
#pragma unroll
      for (int ks = 8; ks < 16; ++ks) {
        half8 ka = *(const half8*)(kb + ks * 512 + lane * 8);
        sB = __builtin_amdgcn_mfma_f32_32x32x16_f16(ka, qh[ks], sB, 0, 0, 0);
      }
      __builtin_amdgcn_s_setprio(0);
    }

    // ---- softmax(kt) on p (VALU; overlaps QK^T(kt+1) MFMA) ----
    float mt = p[0];
#pragma unroll
    for (int i = 1; i < 16; ++i) mt = fmaxf(mt, p[i]);
    mt = fmaxf(mt, __shfl_xor(mt, 32));
    if (__any(mt > m0r + 11.5416f)) {
      float mn = fmaxf(m0r, mt);
      float sc = ex2(m0r - mn);
      l0 *= sc;
#pragma unroll
      for (int dt = 0; dt < 4; ++dt)
#pragma unroll
        for (int i = 0; i < 16; ++i) acc[dt][i] *= sc;
      m0r = mn;
    }
#pragma unroll
    for (int i = 0; i < 16; ++i) p[i] = ex2(p[i] - m0r);
    l0 += (((p[0] + p[1]) + (p[2] + p[3])) + ((p[4] + p[5]) + (p[6] + p[7]))) +
          (((p[8] + p[9]) + (p[10] + p[11])) + ((p[12] + p[13]) + (p[14] + p[15])));
    half8 pa0, pa1;
    {
      uint4v u0 = { pk2(p[0], p[1]), pk2(p[2], p[3]), pk2(p[4], p[5]), pk2(p[6], p[7]) };
      uint4v u1 = { pk2(p[8], p[9]), pk2(p[10], p[11]), pk2(p[12], p[13]), pk2(p[14], p[15]) };
      pa0 = __builtin_bit_cast(half8, u0);
      pa1 = __builtin_bit_cast(half8, u1);
    }

    // ---- PV(kt): own d-half ----
    __builtin_amdgcn_s_setprio(1);
#pragma unroll
    for (int dt = 0; dt < 4; ++dt) {
      acc[dt] = __builtin_amdgcn_mfma_f32_32x32x16_f16(vb[dt * 2 + 0], pa0, acc[dt], 0, 0, 0);
      acc[dt] = __builtin_amdgcn_mfma_f32_32x32x16_f16(vb[dt * 2 + 1], pa1, acc[dt], 0, 0, 0);
    }
    __builtin_amdgcn_s_setprio(0);

    // ---- carry scores for next iteration ----
    if (kt + 1 < NT) {
#pragma unroll
      for (int i = 0; i < 16; ++i) p[i] = sA[i] + sB[i];
    }

    vp += 8192;
    sp += 8192;
    __syncthreads();   // drains DMA(kt+2); kls[(kt+2)&1] ready for next iter's QK^T
  }

  // ---- epilogue ----
  l0 += __shfl_xor(l0, 32);
  float inv0 = 1.0f / l0;
  float* ob = out + ((size_t)b * NI + qbase + l31) * DD + h * 128 + hi * 4;
#pragma unroll
  for (int dt = 0; dt < 4; ++dt) {
#pragma unroll
    for (int rq = 0; rq < 4; ++rq) {
      float4 v;
      v.x = acc[dt][rq * 4 + 0] * inv0;
      v.y = acc[dt][rq * 4 + 1] * inv0;
      v.z = acc[dt][rq * 4 + 2] * inv0;
      v.w = acc[dt][rq * 4 + 3] * inv0;
      *(float4*)(ob + dt * 32 + rq * 8) = v;
    }
  }
}

extern "C" void kernel_launch(void* const* d_in, const int* in_sizes, int n_in,
                              void* d_out, int out_size, void* d_ws, size_t ws_size,
                              hipStream_t stream) {
  const float* x = (const float*)d_in[0];        // [16,2048,256]
  const float* att = (const float*)d_in[1];      // [16,2048,256]
  const float* W = (const float*)d_in[2];        // [256,256]
  float* out = (float*)d_out;

  const size_t NE = (size_t)BB * NA * DD;        // 8388608
  unsigned short* w0    = (unsigned short*)d_ws;
  unsigned short* kfrag = w0;
  unsigned short* vfrag = w0 + NE;
  unsigned short* qfp   = w0 + 2 * NE;
  unsigned short* wth   = w0 + 3 * NE;
  unsigned short* wtl   = w0 + 3 * NE + (size_t)DD * DD;

  prep_kernel<<<2064, 256, 0, stream>>>(att, kfrag, vfrag, W, wth, wtl);
  qgemm_kernel<<<512, 256, 0, stream>>>(x, wth, wtl, qfp);
  attn_kernel<<<512, 256, 0, stream>>>(kfrag, vfrag, qfp, out);
}

// Round 19
// 161.678 us; speedup vs baseline: 1.1415x; 1.1415x over previous
//
#include <hip/hip_runtime.h>
#include <hip/hip_bf16.h>

#define BB 16
#define NI 2048
#define NA 2048
#define DD 256
#define KVB 32
#define NT (NA / KVB)    // 64

typedef _Float16 half8 __attribute__((ext_vector_type(8)));
typedef __attribute__((ext_vector_type(16))) float f32x16;
typedef __attribute__((ext_vector_type(4))) float f32x4;
typedef __attribute__((ext_vector_type(4))) unsigned int uint4v;

typedef const unsigned int CGU __attribute__((address_space(1)));
typedef unsigned int LU __attribute__((address_space(3)));

static __device__ __forceinline__ unsigned short f2h(float f) {
  union { _Float16 h; unsigned short u; } x; x.h = (_Float16)f; return x.u;
}
static __device__ __forceinline__ float h2f(unsigned short u) {
  union { _Float16 h; unsigned short u; } x; x.u = u; return (float)x.h;
}
static __device__ __forceinline__ unsigned int pk2(float a, float b) {
  return __builtin_bit_cast(unsigned int, __builtin_amdgcn_cvt_pkrtz(a, b));
}
static __device__ __forceinline__ float ex2(float x) {
  return __builtin_amdgcn_exp2f(x);
}
static __device__ __forceinline__ void gload16(const unsigned short* g, unsigned short* l) {
  __builtin_amdgcn_global_load_lds((CGU*)g, (LU*)l, 16, 0, 0);
}

// ---------------- prep (+fused W-frag emission) ----------------
// kfrag[b][kt][ks(16)][lane(64)][e(8)]: lane holds K[jb + (l&31)][ks*16 + (l>>5)*8 + e]
// vfrag[b][kt][h(2)][dt(4)][m(2)][lane(64)][e(8)]: lane holds
//   V^T[h*128 + dt*32 + (l&31)][jb + (e&3) + 8*(e>>2) + 4*(l>>5) + 16*m]
// wbf{h,l}[et(16)][c(8)][lane(64)][e(8)]: lane holds W^T[et*16+(l&15)][c*32+(l>>4)*8+e]
//   (16x16x32 B-fragment order: direct coalesced loads in qgemm, no LDS)
__global__ void prep_kernel(const float* __restrict__ a,
                            unsigned short* __restrict__ kfrag,
                            unsigned short* __restrict__ vfrag,
                            const float* __restrict__ w,
                            unsigned short* __restrict__ wbfh,
                            unsigned short* __restrict__ wbfl) {
  __shared__ float t[64][65];
  int bx = blockIdx.x;
  int tid = threadIdx.x;
  int rr = tid >> 4, c4 = tid & 15;

  if (bx >= 2048) {
    // ---- W -> W^T hi/lo fp16 in B-frag order ----
    int r = bx - 2048;
    int dt = r >> 2, et4 = r & 3;
    int d0 = dt * 64, e0 = et4 * 64;
    int cc = c4 * 4;
#pragma unroll
    for (int k = 0; k < 4; ++k) {
      int row = rr + k * 16;   // d index
      float4 v = *(const float4*)(w + (size_t)(d0 + row) * DD + e0 + cc);
      t[row][cc + 0] = v.x; t[row][cc + 1] = v.y; t[row][cc + 2] = v.z; t[row][cc + 3] = v.w;
    }
    __syncthreads();
    int d = d0 + cc;             // 4 consecutive d, same c & quad
    int c = d >> 5;
    int quad = (d >> 3) & 3;
#pragma unroll
    for (int k = 0; k < 4; ++k) {
      int e_local = rr + k * 16;
      int eg = e0 + e_local;
      ushort4 h, l;
      float v0 = t[cc + 0][e_local]; h.x = f2h(v0); l.x = f2h(v0 - h2f(h.x));
      float v1 = t[cc + 1][e_local]; h.y = f2h(v1); l.y = f2h(v1 - h2f(h.y));
      float v2 = t[cc + 2][e_local]; h.z = f2h(v2); l.z = f2h(v2 - h2f(h.z));
      float v3 = t[cc + 3][e_local]; h.w = f2h(v3); l.w = f2h(v3 - h2f(h.w));
      int et = eg >> 4, l16e = eg & 15;
      size_t off = ((size_t)(et * 8 + c) * 64 + quad * 16 + l16e) * 8 + (c4 & 1) * 4;
      *(ushort4*)(wbfh + off) = h;
      *(ushort4*)(wbfl + off) = l;
    }
    return;
  }

  int b = bx >> 7;
  int r = bx & 127;
  int jt_t = r >> 2, dt_t = r & 3;
  int j0 = jt_t * 64, d0 = dt_t * 64;
#pragma unroll
  for (int k = 0; k < 4; ++k) {
    int row = rr + k * 16;
    int j = j0 + row;
    int d = d0 + c4 * 4;
    float4 v = *(const float4*)(a + ((size_t)b * NA + j) * DD + d);
    ushort4 hh;
    hh.x = f2h(v.x); hh.y = f2h(v.y); hh.z = f2h(v.z); hh.w = f2h(v.w);
    int kt = j >> 5;
    int ks = d >> 4;
    int lk = (j & 31) + 32 * ((d >> 3) & 1);
    *(ushort4*)(kfrag + (((size_t)b * NT + kt) * 16 + ks) * 512 + lk * 8 + (c4 & 1) * 4) = hh;
    t[row][c4 * 4 + 0] = v.x; t[row][c4 * 4 + 1] = v.y;
    t[row][c4 * 4 + 2] = v.z; t[row][c4 * 4 + 3] = v.w;
  }
  __syncthreads();
#pragma unroll
  for (int k = 0; k < 4; ++k) {
    int dl = rr + k * 16;
    int d = d0 + dl;
    int j = j0 + c4 * 4;
    ushort4 o;
    o.x = f2h(t[c4 * 4 + 0][dl]); o.y = f2h(t[c4 * 4 + 1][dl]);
    o.z = f2h(t[c4 * 4 + 2][dl]); o.w = f2h(t[c4 * 4 + 3][dl]);
    int kt = j >> 5;
    int hi = c4 & 1;
    int m = (c4 >> 2) & 1;
    int ebase = ((c4 >> 1) & 1) * 4;
    int hh_ = d >> 7, dtl = (d >> 5) & 3;
    int lv = (d & 31) + 32 * hi;
    *(ushort4*)(vfrag + ((((((size_t)b * NT + kt) * 2 + hh_) * 4 + dtl) * 2 + m) * 512) + lv * 8 + ebase) = o;
  }
}

// ---------------- Q = (x @ W) * log2(e): LDS-free, barrier-free, writes qfrag ----------------
// qfrag[qt(q>>5)][ks(16)][lane(64)][e(8)]: lane holds Q[qt*32+(l&31)][ks*16+(l>>5)*8+e]
// (attn's 32x32 B-frag order -> coalesced prologue loads)
__global__ __launch_bounds__(256, 8) void qgemm_kernel(
    const float* __restrict__ x, const unsigned short* __restrict__ wbfh,
    const unsigned short* __restrict__ wbfl, unsigned short* __restrict__ qfrag) {
  const int tid = threadIdx.x;
  const int lane = tid & 63;
  const int wv = tid >> 6;
  const int quad = lane >> 4;
  const int l16 = lane & 15;
  const int m0 = blockIdx.x * 64;

  // x A-frags fp16 (rows q = m0 + wv*16 + l16)
  half8 xf[8];
  {
    const float* xr = x + (size_t)(m0 + wv * 16 + l16) * DD;
#pragma unroll
    for (int c = 0; c < 8; ++c) {
      float4 a = *(const float4*)(xr + c * 32 + quad * 8);
      float4 b = *(const float4*)(xr + c * 32 + quad * 8 + 4);
      half8 v;
      v[0] = (_Float16)a.x; v[1] = (_Float16)a.y; v[2] = (_Float16)a.z; v[3] = (_Float16)a.w;
      v[4] = (_Float16)b.x; v[5] = (_Float16)b.y; v[6] = (_Float16)b.z; v[7] = (_Float16)b.w;
      xf[c] = v;
    }
  }

  const int sub = l16 & 7;
  const int khalf = (l16 >> 3) & 1;
#pragma unroll 1
  for (int et = 0; et < 16; ++et) {
    f32x4 acc; acc[0] = acc[1] = acc[2] = acc[3] = 0.f;
#pragma unroll
    for (int c = 0; c < 8; ++c) {
      half8 wh = *(const half8*)(wbfh + ((size_t)(et * 8 + c) * 64 + lane) * 8);
      half8 wl = *(const half8*)(wbfl + ((size_t)(et * 8 + c) * 64 + lane) * 8);
      acc = __builtin_amdgcn_mfma_f32_16x16x32_f16(xf[c], wh, acc, 0, 0, 0);
      acc = __builtin_amdgcn_mfma_f32_16x16x32_f16(xf[c], wl, acc, 0, 0, 0);
    }
    // C layout: row q = m0+wv*16+4*quad+rg, col e = et*16 + l16  ->  qfrag
#pragma unroll
    for (int rg = 0; rg < 4; ++rg) {
      int qrow = m0 + wv * 16 + 4 * quad + rg;
      int qt = qrow >> 5, l31q = qrow & 31;
      qfrag[((size_t)(qt * 16 + et)) * 512 + (l31q + 32 * khalf) * 8 + sub] =
          f2h(acc[rg] * 1.44269504f);
    }
  }
}

// ---------------- flash attention (v16 structure, coalesced qfrag prologue) ----------------
// 4 waves = 2 pairs x 2 d-halves; each wave computes full 32x32 S^T (16 big MFMA),
// in-lane softmax (q = lane&31, one shfl_xor(32)), zero-shuffle P via co-permuted vfrag.
// K DMA double-buffered, one end-of-body barrier/kt. 2 blocks/CU.
__global__ __launch_bounds__(256, 2) void attn_kernel(
    const unsigned short* __restrict__ kfrag, const unsigned short* __restrict__ vfrag,
    const unsigned short* __restrict__ qfrag, float* __restrict__ out) {
  __shared__ unsigned short kls[2][KVB * DD];   // 2 x 16 KB

  const int tid = threadIdx.x;
  const int lane = tid & 63;
  const int wv = tid >> 6;       // 0..3
  const int pr = wv >> 1;        // pair -> q-group
  const int h = wv & 1;          // d-half
  const int l31 = lane & 31;
  const int hi = lane >> 5;

  int bx = blockIdx.x;
  int lbx = (bx & 7) * 64 + (bx >> 3);   // XCD-chunked (512 = 8*64)
  const int b = lbx >> 5;
  const int qbase = (lbx & 31) * 64 + pr * 32;

  const unsigned short* kfb = kfrag + (size_t)b * NT * 8192;

  // Q B-fragments (32 q x 256 k), coalesced from qfrag
  half8 qh[16];
  {
    const unsigned short* qr = qfrag + ((size_t)((b * NI + qbase) >> 5) * 16) * 512 + lane * 8;
#pragma unroll
    for (int ks = 0; ks < 16; ++ks)
      qh[ks] = *(const half8*)(qr + ks * 512);
  }

  f32x16 acc[4];
#pragma unroll
  for (int dt = 0; dt < 4; ++dt)
#pragma unroll
    for (int i = 0; i < 16; ++i) acc[dt][i] = 0.f;
  float m0r = -INFINITY;
  float l0 = 0.f;

  const unsigned short* vp = vfrag + (((size_t)b * NT * 2 + h) * 4) * 1024 + lane * 8;
  const unsigned short* sp = kfb + 8192 + (wv * 512 + lane * 8);

  // prologue: DMA K tile 0
#pragma unroll
  for (int i = 0; i < 4; ++i) {
    int off = (i * 4 + wv) * 512;
    gload16(kfb + off + lane * 8, &kls[0][off]);
  }
  __syncthreads();

#pragma unroll 1
  for (int kt = 0; kt < NT; ++kt) {
    // ---- V A-frags (own d-half), coalesced from L2 ----
    half8 vb[8];
#pragma unroll
    for (int i = 0; i < 8; ++i)
      vb[i] = *(const half8*)(vp + i * 512);

    // ---- async DMA K(kt+1) ----
    if (kt + 1 < NT) {
      unsigned short* d = &kls[(kt + 1) & 1][wv * 512];
      gload16(sp + 0 * 2048, d + 0 * 2048);
      gload16(sp + 1 * 2048, d + 1 * 2048);
      gload16(sp + 2 * 2048, d + 2 * 2048);
      gload16(sp + 3 * 2048, d + 3 * 2048);
    }

    // ---- QK^T: full 32x32 S^T, 16 big MFMA in 2 chains ----
    const unsigned short* kb = &kls[kt & 1][0];
    f32x16 sA, sB;
#pragma unroll
    for (int i = 0; i < 16; ++i) { sA[i] = 0.f; sB[i] = 0.f; }
    __builtin_amdgcn_s_setprio(1);
#pragma unroll
    for (int ks = 0; ks < 8; ++ks) {
      half8 ka = *(const half8*)(kb + ks * 512 + lane * 8);
      sA = __builtin_amdgcn_mfma_f32_32x32x16_f16(ka, qh[ks], sA, 0, 0, 0);
    }
#pragma unroll
    for (int ks = 8; ks < 16; ++ks) {
      half8 ka = *(const half8*)(kb + ks * 512 + lane * 8);
      sB = __builtin_amdgcn_mfma_f32_32x32x16_f16(ka, qh[ks], sB, 0, 0, 0);
    }
    __builtin_amdgcn_s_setprio(0);
    float p[16];
#pragma unroll
    for (int i = 0; i < 16; ++i) p[i] = sA[i] + sB[i];

    // ---- in-lane softmax over 32 j ----
    float mt = p[0];
#pragma unroll
    for (int i = 1; i < 16; ++i) mt = fmaxf(mt, p[i]);
    mt = fmaxf(mt, __shfl_xor(mt, 32));
    if (__any(mt > m0r + 11.5416f)) {
      float mn = fmaxf(m0r, mt);
      float sc = ex2(m0r - mn);
      l0 *= sc;
#pragma unroll
      for (int dt = 0; dt < 4; ++dt)
#pragma unroll
        for (int i = 0; i < 16; ++i) acc[dt][i] *= sc;
      m0r = mn;
    }

#pragma unroll
    for (int i = 0; i < 16; ++i) p[i] = ex2(p[i] - m0r);
    l0 += (((p[0] + p[1]) + (p[2] + p[3])) + ((p[4] + p[5]) + (p[6] + p[7]))) +
          (((p[8] + p[9]) + (p[10] + p[11])) + ((p[12] + p[13]) + (p[14] + p[15])));

    half8 pa0, pa1;
    {
      uint4v u0 = { pk2(p[0], p[1]), pk2(p[2], p[3]), pk2(p[4], p[5]), pk2(p[6], p[7]) };
      uint4v u1 = { pk2(p[8], p[9]), pk2(p[10], p[11]), pk2(p[12], p[13]), pk2(p[14], p[15]) };
      pa0 = __builtin_bit_cast(half8, u0);
      pa1 = __builtin_bit_cast(half8, u1);
    }

    // ---- PV: own d-half ----
    __builtin_amdgcn_s_setprio(1);
#pragma unroll
    for (int dt = 0; dt < 4; ++dt) {
      acc[dt] = __builtin_amdgcn_mfma_f32_32x32x16_f16(vb[dt * 2 + 0], pa0, acc[dt], 0, 0, 0);
      acc[dt] = __builtin_amdgcn_mfma_f32_32x32x16_f16(vb[dt * 2 + 1], pa1, acc[dt], 0, 0, 0);
    }
    __builtin_amdgcn_s_setprio(0);

    vp += 8192;
    sp += 8192;
    __syncthreads();   // drains DMA for kt+1
  }

  // ---- epilogue ----
  l0 += __shfl_xor(l0, 32);
  float inv0 = 1.0f / l0;
  float* ob = out + ((size_t)b * NI + qbase + l31) * DD + h * 128 + hi * 4;
#pragma unroll
  for (int dt = 0; dt < 4; ++dt) {
#pragma unroll
    for (int rq = 0; rq < 4; ++rq) {
      float4 v;
      v.x = acc[dt][rq * 4 + 0] * inv0;
      v.y = acc[dt][rq * 4 + 1] * inv0;
      v.z = acc[dt][rq * 4 + 2] * inv0;
      v.w = acc[dt][rq * 4 + 3] * inv0;
      *(float4*)(ob + dt * 32 + rq * 8) = v;
    }
  }
}

extern "C" void kernel_launch(void* const* d_in, const int* in_sizes, int n_in,
                              void* d_out, int out_size, void* d_ws, size_t ws_size,
                              hipStream_t stream) {
  const float* x = (const float*)d_in[0];        // [16,2048,256]
  const float* att = (const float*)d_in[1];      // [16,2048,256]
  const float* W = (const float*)d_in[2];        // [256,256]
  float* out = (float*)d_out;

  const size_t NE = (size_t)BB * NA * DD;        // 8388608
  unsigned short* w0    = (unsigned short*)d_ws;
  unsigned short* kfrag = w0;
  unsigned short* vfrag = w0 + NE;
  unsigned short* qfrag = w0 + 2 * NE;
  unsigned short* wbfh  = w0 + 3 * NE;
  unsigned short* wbfl  = w0 + 3 * NE + 65536;

  prep_kernel<<<2064, 256, 0, stream>>>(att, kfrag, vfrag, W, wbfh, wbfl);
  qgemm_kernel<<<512, 256, 0, stream>>>(x, wbfh, wbfl, qfrag);
  attn_kernel<<<512, 256, 0, stream>>>(kfrag, vfrag, qfrag, out);
}